// Round 25
// baseline (192.818 us; speedup 1.0000x reference)
//
#include <hip/hip_runtime.h>
#include <hip/hip_bf16.h>

// FraudSNN fused kernel: GEMM (bf16 MFMA) + LIF recurrence, T=10, F=256, H=512.
// R25: mem1 moved from LDS to REGISTERS (32 VGPR/thread at 32 rows / 512 thr).
// R7-R23 kept mem1 in LDS because of the 64-reg-budget era; the R21 frame runs at
// the 120-reg budget with only 32 acc regs -> mem1 fits. This deletes the LIF
// phase's chain of 6 dependent ds_read(120cyc)->VALU->ds_write round-trips (~1-2K
// cyc/t/wave, barrier-locked so occupancy couldn't hide it - R24's null result).
// kk0-hoist dropped to free 32 held regs. Frame else = R21: 1 barrier/t, deferred
// LIF2, parity-dbuf xt, setprio. LDS 45.3 KB; persistent live ~58, GEMM peak ~125.

typedef short short8 __attribute__((ext_vector_type(8)));
typedef float f32x4 __attribute__((ext_vector_type(4)));

__device__ __forceinline__ unsigned short bfbits(float f) {
  union { __hip_bfloat16 h; unsigned short u; } c;
  c.h = __float2bfloat16(f);   // hardware RNE
  return c.u;
}

__device__ __forceinline__ unsigned int bfpack(float a, float b) {
  return (unsigned int)bfbits(a) | ((unsigned int)bfbits(b) << 16);
}

__device__ __forceinline__ float fast_sigmoid(float z) {
  float e = __expf(-z);
  return __builtin_amdgcn_rcpf(1.0f + e);
}

__device__ __forceinline__ void lif4(f32x4& mv, const f32x4 av, float w2c, float pr[4]) {
#pragma unroll
  for (int e = 0; e < 4; ++e) {
    float m   = fmaf(mv[e], 0.9f, av[e]);     // beta*mem + cur1
    float spk = fast_sigmoid(fmaf(m, 10.f, -10.f));
    mv[e] = m - spk;
    pr[e] = fmaf(spk, w2c, pr[e]);
  }
}

__global__ void w1_to_bf16(const float* __restrict__ w1, unsigned short* __restrict__ o) {
  int i = blockIdx.x * 256 + threadIdx.x;      // 32768 float4s
  float4 v = reinterpret_cast<const float4*>(w1)[i];
  reinterpret_cast<uint2*>(o)[i] = make_uint2(bfpack(v.x, v.y), bfpack(v.z, v.w));
}

__device__ __forceinline__ short8 cvt_frag(const float* p) {
  const float4 v0 = *reinterpret_cast<const float4*>(p);
  const float4 v1 = *reinterpret_cast<const float4*>(p + 4);
  union { unsigned int u[4]; short8 s; } cv;
  cv.u[0] = bfpack(v0.x, v0.y);
  cv.u[1] = bfpack(v0.z, v0.w);
  cv.u[2] = bfpack(v1.x, v1.y);
  cv.u[3] = bfpack(v1.z, v1.w);
  return cv.s;
}

// 512 threads = 8 waves. Block: 32 batch rows; wave w owns 32 rows x h in [w*64, w*64+64).
template <bool USE_WS>
__global__
__attribute__((amdgpu_flat_work_group_size(512, 512)))
void snn_main(const float* __restrict__ x,
              const unsigned short* __restrict__ w1bf,  // bf16 W1 (if USE_WS)
              const float* __restrict__ w1f,            // fp32 W1 (fallback)
              const float* __restrict__ b1,
              const float* __restrict__ w2,
              const float* __restrict__ b2,
              float* __restrict__ out)
{
  __shared__ __align__(16) unsigned short xt[2][2][32][132];  // [par][half][row][col] 33,792 B
  __shared__ float cur2_lds[10][32][9];                       // [t][row][wave] 11,520 B
                                                              // total 45,312 B

  const int tid  = threadIdx.x;
  const int lane = tid & 63;
  const int wave = tid >> 6;          // 0..7
  const int l15  = lane & 15;
  const int lq   = lane >> 4;         // 0..3
  const long b0  = (long)blockIdx.x * 32;
  const int h0   = wave * 64;         // 4 col-tiles of 16

  float w2l[4], b1l[4];
#pragma unroll
  for (int ct = 0; ct < 4; ++ct) {
    int h = h0 + ct * 16 + l15;
    w2l[ct] = w2[h];
    b1l[ct] = b1[h];
  }

  // mem1 fully in registers: [rt][c] = 8 x f32x4 = 32 VGPR
  f32x4 mem1r[2][4];
#pragma unroll
  for (int rt = 0; rt < 2; ++rt)
#pragma unroll
    for (int c = 0; c < 4; ++c) {
      f32x4 z = {0.f, 0.f, 0.f, 0.f};
      mem1r[rt][c] = z;
    }

  // staging: thread -> row sr (0..31), float4 col sc (0..15); 4 float4 per t
  const int sr = tid >> 4;
  const int sc = tid & 15;
  const float* xrow = x + (b0 + sr) * 2560;

  const unsigned short* wb = w1bf + (h0 + l15) * 256 + lq * 8;
  const float*          wf = w1f  + (h0 + l15) * 256 + lq * 8;

  // prologue: load+pack t=0 (pf = 4 uint2 = 8 VGPR)
  uint2 pf[4];
#pragma unroll
  for (int j = 0; j < 4; ++j) {
    const float4 v = *reinterpret_cast<const float4*>(xrow + (sc + j * 16) * 4);
    pf[j] = make_uint2(bfpack(v.x, v.y), bfpack(v.z, v.w));
  }

#pragma unroll 1
  for (int t = 0; t < 10; ++t) {
    const int par = t & 1;
    // ---- A: write pf(t) -> xt[par]; issue+pack loads for t+1 (full-phase cover).
    //      xt[par] was last read at compute(t-2); bar(t-1) separates -> safe. ----
#pragma unroll
    for (int j = 0; j < 4; ++j)
      *reinterpret_cast<uint2*>(
          &xt[par][j >> 1][sr][(sc + (j & 1) * 16) * 4]) = pf[j];
    {
      const int tn = (t < 9) ? t + 1 : 9;   // tail: harmless re-read
#pragma unroll
      for (int j = 0; j < 4; ++j) {
        const float4 v = *reinterpret_cast<const float4*>(
            xrow + tn * 256 + (sc + j * 16) * 4);
        pf[j] = make_uint2(bfpack(v.x, v.y), bfpack(v.z, v.w));
      }
    }
    __syncthreads();   // the ONLY per-t barrier: xt[par] visible

    // ---- single-pass GEMM: acc[2][4] = 32 regs, 8 MFMA per kk ----
    f32x4 acc[2][4];
#pragma unroll
    for (int rt = 0; rt < 2; ++rt)
#pragma unroll
      for (int c = 0; c < 4; ++c) {
        f32x4 cc = { b1l[c], b1l[c], b1l[c], b1l[c] };
        acc[rt][c] = cc;
      }

    __builtin_amdgcn_s_setprio(1);
#pragma unroll
    for (int kk = 0; kk < 8; ++kk) {
      short8 a[2], bfr[4];
#pragma unroll
      for (int rt = 0; rt < 2; ++rt)
        a[rt] = *reinterpret_cast<const short8*>(
            &xt[par][kk >> 2][rt * 16 + l15][(kk & 3) * 32 + lq * 8]);
#pragma unroll
      for (int c = 0; c < 4; ++c) {
        if constexpr (USE_WS)
          bfr[c] = *reinterpret_cast<const short8*>(wb + c * 4096 + kk * 32);
        else
          bfr[c] = cvt_frag(wf + c * 4096 + kk * 32);
      }
#pragma unroll
      for (int rt = 0; rt < 2; ++rt)
#pragma unroll
        for (int c = 0; c < 4; ++c)
          acc[rt][c] = __builtin_amdgcn_mfma_f32_16x16x32_bf16(a[rt], bfr[c], acc[rt][c], 0, 0, 0);
    }
    __builtin_amdgcn_s_setprio(0);

    // ---- LIF1 + partial W2 dot; mem1 in REGISTERS (pure VALU, no LDS latency) ----
#pragma unroll
    for (int rt = 0; rt < 2; ++rt) {
      float pr[4] = {0.f, 0.f, 0.f, 0.f};
#pragma unroll
      for (int c = 0; c < 4; ++c)
        lif4(mem1r[rt][c], acc[rt][c], w2l[c], pr);
#pragma unroll
      for (int e = 0; e < 4; ++e) {
        float v = pr[e];
        v += __shfl_xor(v, 1); v += __shfl_xor(v, 2);
        v += __shfl_xor(v, 4); v += __shfl_xor(v, 8);
        if (l15 == 0) cur2_lds[t][rt * 16 + lq * 4 + e][wave] = v;
      }
    }
    // no second barrier: cur2_lds[t] is not read until after the final barrier
  }

  __syncthreads();   // final: all cur2 partials visible

  // ---- deferred LIF2: 10-step chain, once, on 32 threads ----
  if (tid < 32) {
    const float bias2 = b2[0];
    float mem2 = 0.f, spksum = 0.f;
#pragma unroll
    for (int t = 0; t < 10; ++t) {
      float c2 = bias2;
#pragma unroll
      for (int w = 0; w < 8; ++w) c2 += cur2_lds[t][tid][w];
      float m   = fmaf(mem2, 0.9f, c2);
      float spk = fast_sigmoid(fmaf(m, 10.f, -10.f));
      mem2   = m - spk;
      spksum += spk;
    }
    out[b0 + tid] = fast_sigmoid(spksum * 0.1f);   // FLOAT32 output
  }
}

extern "C" void kernel_launch(void* const* d_in, const int* in_sizes, int n_in,
                              void* d_out, int out_size, void* d_ws, size_t ws_size,
                              hipStream_t stream) {
  const float* x  = (const float*)d_in[0];
  const float* W1 = (const float*)d_in[1];
  const float* b1 = (const float*)d_in[2];
  const float* W2 = (const float*)d_in[3];
  const float* b2 = (const float*)d_in[4];
  float* out = (float*)d_out;
  (void)in_sizes; (void)n_in;

  const int grid = out_size / 32;   // out_size == B == 32768 -> 1024 blocks

  if (ws_size >= 512 * 256 * sizeof(unsigned short)) {
    unsigned short* w1bf = (unsigned short*)d_ws;   // 256 KB
    w1_to_bf16<<<128, 256, 0, stream>>>(W1, w1bf);
    snn_main<true><<<grid, 512, 0, stream>>>(x, w1bf, W1, b1, W2, b2, out);
  } else {
    snn_main<false><<<grid, 512, 0, stream>>>(x, nullptr, W1, b1, W2, b2, out);
  }
}

// Round 27
// 171.709 us; speedup vs baseline: 1.1229x; 1.1229x over previous
//
#include <hip/hip_runtime.h>
#include <hip/hip_bf16.h>

// FraudSNN fused kernel: GEMM (bf16 MFMA) + LIF recurrence, T=10, F=256, H=512.
// R27 = R26 with the compile fix (__exp2f -> __builtin_amdgcn_exp2f):
//  - w1s stride 68 shorts (34 dw): bank = (2*l15 + 4*lq) mod 32 = xt's PROVEN
//    0-conflict pattern (R23's 72 gave 8-way, 2.6M conflict cycles).
//  - sigmoid via exp2: sigmoid(10m-10) = 1/(1+exp2(14.427-14.427m)).
// Frame: 1 barrier/t, deferred LIF2, parity-dbuf xt, mem1 5 LDS planes + 3 reg
// planes, kk=2 hoist, setprio. LDS 155.9 KB; live ~120.

typedef short short8 __attribute__((ext_vector_type(8)));
typedef float f32x4 __attribute__((ext_vector_type(4)));

__device__ __forceinline__ unsigned short bfbits(float f) {
  union { __hip_bfloat16 h; unsigned short u; } c;
  c.h = __float2bfloat16(f);   // hardware RNE
  return c.u;
}

__device__ __forceinline__ unsigned int bfpack(float a, float b) {
  return (unsigned int)bfbits(a) | ((unsigned int)bfbits(b) << 16);
}

// sigmoid(10*(m-1)) = 1 / (1 + exp2(14.4269504*(1-m)))
__device__ __forceinline__ float spike10(float m) {
  float e = __builtin_amdgcn_exp2f(fmaf(m, -14.4269504f, 14.4269504f));
  return __builtin_amdgcn_rcpf(1.0f + e);
}

__device__ __forceinline__ void lif4(f32x4& mv, const f32x4 av, float w2c, float pr[4]) {
#pragma unroll
  for (int e = 0; e < 4; ++e) {
    float m   = fmaf(mv[e], 0.9f, av[e]);     // beta*mem + cur1
    float spk = spike10(m);
    mv[e] = m - spk;
    pr[e] = fmaf(spk, w2c, pr[e]);
  }
}

__global__ void w1_to_bf16(const float* __restrict__ w1, unsigned short* __restrict__ o) {
  int i = blockIdx.x * 256 + threadIdx.x;      // 32768 float4s
  float4 v = reinterpret_cast<const float4*>(w1)[i];
  reinterpret_cast<uint2*>(o)[i] = make_uint2(bfpack(v.x, v.y), bfpack(v.z, v.w));
}

__device__ __forceinline__ short8 cvt_frag(const float* p) {
  const float4 v0 = *reinterpret_cast<const float4*>(p);
  const float4 v1 = *reinterpret_cast<const float4*>(p + 4);
  union { unsigned int u[4]; short8 s; } cv;
  cv.u[0] = bfpack(v0.x, v0.y);
  cv.u[1] = bfpack(v0.z, v0.w);
  cv.u[2] = bfpack(v1.x, v1.y);
  cv.u[3] = bfpack(v1.z, v1.w);
  return cv.s;
}

// 512 threads = 8 waves. Block: 32 batch rows; wave w owns 32 rows x h in [w*64, w*64+64).
template <bool USE_WS>
__global__
__attribute__((amdgpu_flat_work_group_size(512, 512)))
void snn_main(const float* __restrict__ x,
              const unsigned short* __restrict__ w1bf,  // bf16 W1 (if USE_WS)
              const float* __restrict__ w1f,            // fp32 W1 (fallback)
              const float* __restrict__ b1,
              const float* __restrict__ w2,
              const float* __restrict__ b2,
              float* __restrict__ out)
{
  __shared__ __align__(16) float mem_lds[5][512][4];          // 40,960 B, 0-conflict slots
  __shared__ __align__(16) unsigned short xt[2][2][32][132];  // [par][half][row][col] 33,792 B
  __shared__ __align__(16) unsigned short w1s[512][68];       // W1 kk0-1 slice, 69,632 B
  __shared__ float cur2_lds[10][32][9];                       // [t][row][wave] 11,520 B
                                                              // total 155,904 B

  const int tid  = threadIdx.x;
  const int lane = tid & 63;
  const int wave = tid >> 6;          // 0..7
  const int l15  = lane & 15;
  const int lq   = lane >> 4;         // 0..3
  const long b0  = (long)blockIdx.x * 32;
  const int h0   = wave * 64;         // 4 col-tiles of 16

  float w2l[4], b1l[4];
#pragma unroll
  for (int ct = 0; ct < 4; ++ct) {
    int h = h0 + ct * 16 + l15;
    w2l[ct] = w2[h];
    b1l[ct] = b1[h];
  }

#pragma unroll
  for (int p = 0; p < 5; ++p) {
    f32x4 z = {0.f, 0.f, 0.f, 0.f};
    *reinterpret_cast<f32x4*>(&mem_lds[p][tid][0]) = z;
  }
  f32x4 m5 = {0.f, 0.f, 0.f, 0.f}, m6 = m5, m7 = m5;  // planes 5,6,7 (rt1 ct1/2/3)

  // ---- stage W1 kk0-1 slice -> LDS, once per block (fenced by t=0's barrier) ----
  // thread tid stages h-row tid: 64 bf16 = 128 B -> w1s[tid][0..63]
  if constexpr (USE_WS) {
    const unsigned short* src = w1bf + tid * 256;
#pragma unroll
    for (int j = 0; j < 8; ++j)
      *reinterpret_cast<uint4*>(&w1s[tid][j * 8]) =
          *reinterpret_cast<const uint4*>(src + j * 8);
  } else {
    const float* src = w1f + tid * 256;
#pragma unroll
    for (int j = 0; j < 8; ++j) {
      short8 s = cvt_frag(src + j * 8);
      *reinterpret_cast<short8*>(&w1s[tid][j * 8]) = s;
    }
  }

  // staging: thread -> row sr (0..31), float4 col sc (0..15); 4 float4 per t
  const int sr = tid >> 4;
  const int sc = tid & 15;
  const float* xrow = x + (b0 + sr) * 2560;

  const unsigned short* wb = w1bf + (h0 + l15) * 256 + lq * 8;
  const float*          wf = w1f  + (h0 + l15) * 256 + lq * 8;

  // prologue: load+pack t=0 (pf = 4 uint2 = 8 VGPR)
  uint2 pf[4];
#pragma unroll
  for (int j = 0; j < 4; ++j) {
    const float4 v = *reinterpret_cast<const float4*>(xrow + (sc + j * 16) * 4);
    pf[j] = make_uint2(bfpack(v.x, v.y), bfpack(v.z, v.w));
  }

#pragma unroll 1
  for (int t = 0; t < 10; ++t) {
    const int par = t & 1;
    // ---- A: write pf(t) -> xt[par]; issue+pack loads for t+1 (full-phase cover).
    //      xt[par] was last read at compute(t-2); bar(t-1) separates -> safe. ----
#pragma unroll
    for (int j = 0; j < 4; ++j)
      *reinterpret_cast<uint2*>(
          &xt[par][j >> 1][sr][(sc + (j & 1) * 16) * 4]) = pf[j];
    {
      const int tn = (t < 9) ? t + 1 : 9;   // tail: harmless re-read
#pragma unroll
      for (int j = 0; j < 4; ++j) {
        const float4 v = *reinterpret_cast<const float4*>(
            xrow + tn * 256 + (sc + j * 16) * 4);
        pf[j] = make_uint2(bfpack(v.x, v.y), bfpack(v.z, v.w));
      }
    }
    // hoist kk=2 W1 fragments above the barrier (first L2 kk; latency under barrier)
    short8 bfr0[4];
#pragma unroll
    for (int c = 0; c < 4; ++c) {
      if constexpr (USE_WS) bfr0[c] = *reinterpret_cast<const short8*>(wb + c * 4096 + 2 * 32);
      else                  bfr0[c] = cvt_frag(wf + c * 4096 + 2 * 32);
    }
    __syncthreads();   // the ONLY per-t barrier: xt[par] (and, at t=0, w1s) visible

    // ---- single-pass GEMM: acc[2][4] = 32 regs, 8 MFMA per kk ----
    f32x4 acc[2][4];
#pragma unroll
    for (int rt = 0; rt < 2; ++rt)
#pragma unroll
      for (int c = 0; c < 4; ++c) {
        f32x4 cc = { b1l[c], b1l[c], b1l[c], b1l[c] };
        acc[rt][c] = cc;
      }

    __builtin_amdgcn_s_setprio(1);
#pragma unroll
    for (int kk = 0; kk < 8; ++kk) {
      short8 a[2], bfr[4];
#pragma unroll
      for (int rt = 0; rt < 2; ++rt)
        a[rt] = *reinterpret_cast<const short8*>(
            &xt[par][kk >> 2][rt * 16 + l15][(kk & 3) * 32 + lq * 8]);
      if (kk < 2) {
        // W1 from LDS slice; stride 34 dw -> bank = 2*l15+4*lq pattern (0-conflict)
#pragma unroll
        for (int c = 0; c < 4; ++c)
          bfr[c] = *reinterpret_cast<const short8*>(
              &w1s[h0 + c * 16 + l15][kk * 32 + lq * 8]);
      } else if (kk == 2) {
#pragma unroll
        for (int c = 0; c < 4; ++c) bfr[c] = bfr0[c];
      } else {
#pragma unroll
        for (int c = 0; c < 4; ++c) {
          if constexpr (USE_WS)
            bfr[c] = *reinterpret_cast<const short8*>(wb + c * 4096 + kk * 32);
          else
            bfr[c] = cvt_frag(wf + c * 4096 + kk * 32);
        }
      }
#pragma unroll
      for (int rt = 0; rt < 2; ++rt)
#pragma unroll
        for (int c = 0; c < 4; ++c)
          acc[rt][c] = __builtin_amdgcn_mfma_f32_16x16x32_bf16(a[rt], bfr[c], acc[rt][c], 0, 0, 0);
    }
    __builtin_amdgcn_s_setprio(0);

    // ---- LIF1 + partial W2 dot; planes 0..4 in LDS, 5..7 in regs ----
#pragma unroll
    for (int rt = 0; rt < 2; ++rt) {
      float pr[4] = {0.f, 0.f, 0.f, 0.f};
#pragma unroll
      for (int c = 0; c < 4; ++c) {
        const int p = rt * 4 + c;
        if (p < 5) {
          f32x4* slot = reinterpret_cast<f32x4*>(&mem_lds[p][tid][0]);
          f32x4 mv = *slot;
          lif4(mv, acc[rt][c], w2l[c], pr);
          *slot = mv;
        } else if (p == 5) {
          lif4(m5, acc[rt][c], w2l[c], pr);
        } else if (p == 6) {
          lif4(m6, acc[rt][c], w2l[c], pr);
        } else {
          lif4(m7, acc[rt][c], w2l[c], pr);
        }
      }
#pragma unroll
      for (int e = 0; e < 4; ++e) {
        float v = pr[e];
        v += __shfl_xor(v, 1); v += __shfl_xor(v, 2);
        v += __shfl_xor(v, 4); v += __shfl_xor(v, 8);
        if (l15 == 0) cur2_lds[t][rt * 16 + lq * 4 + e][wave] = v;
      }
    }
    // no second barrier: cur2_lds[t] is not read until after the final barrier
  }

  __syncthreads();   // final: all cur2 partials visible

  // ---- deferred LIF2: 10-step chain, once, on 32 threads ----
  if (tid < 32) {
    const float bias2 = b2[0];
    float mem2 = 0.f, spksum = 0.f;
#pragma unroll
    for (int t = 0; t < 10; ++t) {
      float c2 = bias2;
#pragma unroll
      for (int w = 0; w < 8; ++w) c2 += cur2_lds[t][tid][w];
      float m   = fmaf(mem2, 0.9f, c2);
      float spk = spike10(m);
      mem2   = m - spk;
      spksum += spk;
    }
    // final output sigmoid(spksum/10)
    float e = __builtin_amdgcn_exp2f(spksum * -0.14426950408f);
    out[b0 + tid] = __builtin_amdgcn_rcpf(1.0f + e);   // FLOAT32 output
  }
}

extern "C" void kernel_launch(void* const* d_in, const int* in_sizes, int n_in,
                              void* d_out, int out_size, void* d_ws, size_t ws_size,
                              hipStream_t stream) {
  const float* x  = (const float*)d_in[0];
  const float* W1 = (const float*)d_in[1];
  const float* b1 = (const float*)d_in[2];
  const float* W2 = (const float*)d_in[3];
  const float* b2 = (const float*)d_in[4];
  float* out = (float*)d_out;
  (void)in_sizes; (void)n_in;

  const int grid = out_size / 32;   // out_size == B == 32768 -> 1024 blocks

  if (ws_size >= 512 * 256 * sizeof(unsigned short)) {
    unsigned short* w1bf = (unsigned short*)d_ws;   // 256 KB
    w1_to_bf16<<<128, 256, 0, stream>>>(W1, w1bf);
    snn_main<true><<<grid, 512, 0, stream>>>(x, w1bf, W1, b1, W2, b2, out);
  } else {
    snn_main<false><<<grid, 512, 0, stream>>>(x, nullptr, W1, b1, W2, b2, out);
  }
}

// Round 28
// 168.709 us; speedup vs baseline: 1.1429x; 1.0178x over previous
//
#include <hip/hip_runtime.h>
#include <hip/hip_bf16.h>

// FraudSNN fused kernel: GEMM (bf16 MFMA) + LIF recurrence, T=10, F=256, H=512.
// R28: 2-blocks/CU experiment. R27's frame shrunk to 78,080 B LDS (<= 81,920 =
// half the 160KB pool) so TWO independent 8-wave blocks can co-reside per CU:
// independent barrier groups overlap each other's staging/GEMM/LIF phases (the
// exposure no within-block trick could hide). Changes vs R27: w1s cache dropped
// (-70KB, was worth ~2us), mem1 = 4 LDS planes + 4 reg planes (m4-m7), kk=0 hoist
// restored. VGPR live ~120 <= 128 budget; 16 waves x 128 VGPR = exact file fit.

typedef short short8 __attribute__((ext_vector_type(8)));
typedef float f32x4 __attribute__((ext_vector_type(4)));

__device__ __forceinline__ unsigned short bfbits(float f) {
  union { __hip_bfloat16 h; unsigned short u; } c;
  c.h = __float2bfloat16(f);   // hardware RNE
  return c.u;
}

__device__ __forceinline__ unsigned int bfpack(float a, float b) {
  return (unsigned int)bfbits(a) | ((unsigned int)bfbits(b) << 16);
}

// sigmoid(10*(m-1)) = 1 / (1 + exp2(14.4269504*(1-m)))
__device__ __forceinline__ float spike10(float m) {
  float e = __builtin_amdgcn_exp2f(fmaf(m, -14.4269504f, 14.4269504f));
  return __builtin_amdgcn_rcpf(1.0f + e);
}

__device__ __forceinline__ void lif4(f32x4& mv, const f32x4 av, float w2c, float pr[4]) {
#pragma unroll
  for (int e = 0; e < 4; ++e) {
    float m   = fmaf(mv[e], 0.9f, av[e]);     // beta*mem + cur1
    float spk = spike10(m);
    mv[e] = m - spk;
    pr[e] = fmaf(spk, w2c, pr[e]);
  }
}

__global__ void w1_to_bf16(const float* __restrict__ w1, unsigned short* __restrict__ o) {
  int i = blockIdx.x * 256 + threadIdx.x;      // 32768 float4s
  float4 v = reinterpret_cast<const float4*>(w1)[i];
  reinterpret_cast<uint2*>(o)[i] = make_uint2(bfpack(v.x, v.y), bfpack(v.z, v.w));
}

__device__ __forceinline__ short8 cvt_frag(const float* p) {
  const float4 v0 = *reinterpret_cast<const float4*>(p);
  const float4 v1 = *reinterpret_cast<const float4*>(p + 4);
  union { unsigned int u[4]; short8 s; } cv;
  cv.u[0] = bfpack(v0.x, v0.y);
  cv.u[1] = bfpack(v0.z, v0.w);
  cv.u[2] = bfpack(v1.x, v1.y);
  cv.u[3] = bfpack(v1.z, v1.w);
  return cv.s;
}

// 512 threads = 8 waves. Block: 32 batch rows; wave w owns 32 rows x h in [w*64, w*64+64).
template <bool USE_WS>
__global__
__attribute__((amdgpu_flat_work_group_size(512, 512)))
void snn_main(const float* __restrict__ x,
              const unsigned short* __restrict__ w1bf,  // bf16 W1 (if USE_WS)
              const float* __restrict__ w1f,            // fp32 W1 (fallback)
              const float* __restrict__ b1,
              const float* __restrict__ w2,
              const float* __restrict__ b2,
              float* __restrict__ out)
{
  __shared__ __align__(16) float mem_lds[4][512][4];          // 32,768 B, 0-conflict slots
  __shared__ __align__(16) unsigned short xt[2][2][32][132];  // [par][half][row][col] 33,792 B
  __shared__ float cur2_lds[10][32][9];                       // [t][row][wave] 11,520 B
                                                              // total 78,080 B (2 blk/CU fits)

  const int tid  = threadIdx.x;
  const int lane = tid & 63;
  const int wave = tid >> 6;          // 0..7
  const int l15  = lane & 15;
  const int lq   = lane >> 4;         // 0..3
  const long b0  = (long)blockIdx.x * 32;
  const int h0   = wave * 64;         // 4 col-tiles of 16

  float w2l[4], b1l[4];
#pragma unroll
  for (int ct = 0; ct < 4; ++ct) {
    int h = h0 + ct * 16 + l15;
    w2l[ct] = w2[h];
    b1l[ct] = b1[h];
  }

#pragma unroll
  for (int p = 0; p < 4; ++p) {
    f32x4 z = {0.f, 0.f, 0.f, 0.f};
    *reinterpret_cast<f32x4*>(&mem_lds[p][tid][0]) = z;
  }
  // planes 4..7 (rt1, all ct) in registers: 16 VGPR
  f32x4 m4 = {0.f, 0.f, 0.f, 0.f}, m5 = m4, m6 = m4, m7 = m4;

  // staging: thread -> row sr (0..31), float4 col sc (0..15); 4 float4 per t
  const int sr = tid >> 4;
  const int sc = tid & 15;
  const float* xrow = x + (b0 + sr) * 2560;

  const unsigned short* wb = w1bf + (h0 + l15) * 256 + lq * 8;
  const float*          wf = w1f  + (h0 + l15) * 256 + lq * 8;

  // prologue: load+pack t=0 (pf = 4 uint2 = 8 VGPR)
  uint2 pf[4];
#pragma unroll
  for (int j = 0; j < 4; ++j) {
    const float4 v = *reinterpret_cast<const float4*>(xrow + (sc + j * 16) * 4);
    pf[j] = make_uint2(bfpack(v.x, v.y), bfpack(v.z, v.w));
  }

#pragma unroll 1
  for (int t = 0; t < 10; ++t) {
    const int par = t & 1;
    // ---- A: write pf(t) -> xt[par]; issue+pack loads for t+1 (full-phase cover).
    //      xt[par] was last read at compute(t-2); bar(t-1) separates -> safe. ----
#pragma unroll
    for (int j = 0; j < 4; ++j)
      *reinterpret_cast<uint2*>(
          &xt[par][j >> 1][sr][(sc + (j & 1) * 16) * 4]) = pf[j];
    {
      const int tn = (t < 9) ? t + 1 : 9;   // tail: harmless re-read
#pragma unroll
      for (int j = 0; j < 4; ++j) {
        const float4 v = *reinterpret_cast<const float4*>(
            xrow + tn * 256 + (sc + j * 16) * 4);
        pf[j] = make_uint2(bfpack(v.x, v.y), bfpack(v.z, v.w));
      }
    }
    // hoist kk=0 W1 fragments above the barrier (L2 latency covered by barrier wait)
    short8 bfr0[4];
#pragma unroll
    for (int c = 0; c < 4; ++c) {
      if constexpr (USE_WS) bfr0[c] = *reinterpret_cast<const short8*>(wb + c * 4096);
      else                  bfr0[c] = cvt_frag(wf + c * 4096);
    }
    __syncthreads();   // the ONLY per-t barrier: xt[par] visible

    // ---- single-pass GEMM: acc[2][4] = 32 regs, 8 MFMA per kk ----
    f32x4 acc[2][4];
#pragma unroll
    for (int rt = 0; rt < 2; ++rt)
#pragma unroll
      for (int c = 0; c < 4; ++c) {
        f32x4 cc = { b1l[c], b1l[c], b1l[c], b1l[c] };
        acc[rt][c] = cc;
      }

    __builtin_amdgcn_s_setprio(1);
#pragma unroll
    for (int kk = 0; kk < 8; ++kk) {
      short8 a[2], bfr[4];
#pragma unroll
      for (int rt = 0; rt < 2; ++rt)
        a[rt] = *reinterpret_cast<const short8*>(
            &xt[par][kk >> 2][rt * 16 + l15][(kk & 3) * 32 + lq * 8]);
      if (kk == 0) {
#pragma unroll
        for (int c = 0; c < 4; ++c) bfr[c] = bfr0[c];
      } else {
#pragma unroll
        for (int c = 0; c < 4; ++c) {
          if constexpr (USE_WS)
            bfr[c] = *reinterpret_cast<const short8*>(wb + c * 4096 + kk * 32);
          else
            bfr[c] = cvt_frag(wf + c * 4096 + kk * 32);
        }
      }
#pragma unroll
      for (int rt = 0; rt < 2; ++rt)
#pragma unroll
        for (int c = 0; c < 4; ++c)
          acc[rt][c] = __builtin_amdgcn_mfma_f32_16x16x32_bf16(a[rt], bfr[c], acc[rt][c], 0, 0, 0);
    }
    __builtin_amdgcn_s_setprio(0);

    // ---- LIF1 + partial W2 dot; planes 0..3 in LDS, 4..7 in regs ----
#pragma unroll
    for (int rt = 0; rt < 2; ++rt) {
      float pr[4] = {0.f, 0.f, 0.f, 0.f};
#pragma unroll
      for (int c = 0; c < 4; ++c) {
        const int p = rt * 4 + c;
        if (p < 4) {
          f32x4* slot = reinterpret_cast<f32x4*>(&mem_lds[p][tid][0]);
          f32x4 mv = *slot;
          lif4(mv, acc[rt][c], w2l[c], pr);
          *slot = mv;
        } else if (p == 4) {
          lif4(m4, acc[rt][c], w2l[c], pr);
        } else if (p == 5) {
          lif4(m5, acc[rt][c], w2l[c], pr);
        } else if (p == 6) {
          lif4(m6, acc[rt][c], w2l[c], pr);
        } else {
          lif4(m7, acc[rt][c], w2l[c], pr);
        }
      }
#pragma unroll
      for (int e = 0; e < 4; ++e) {
        float v = pr[e];
        v += __shfl_xor(v, 1); v += __shfl_xor(v, 2);
        v += __shfl_xor(v, 4); v += __shfl_xor(v, 8);
        if (l15 == 0) cur2_lds[t][rt * 16 + lq * 4 + e][wave] = v;
      }
    }
    // no second barrier: cur2_lds[t] is not read until after the final barrier
  }

  __syncthreads();   // final: all cur2 partials visible

  // ---- deferred LIF2: 10-step chain, once, on 32 threads ----
  if (tid < 32) {
    const float bias2 = b2[0];
    float mem2 = 0.f, spksum = 0.f;
#pragma unroll
    for (int t = 0; t < 10; ++t) {
      float c2 = bias2;
#pragma unroll
      for (int w = 0; w < 8; ++w) c2 += cur2_lds[t][tid][w];
      float m   = fmaf(mem2, 0.9f, c2);
      float spk = spike10(m);
      mem2   = m - spk;
      spksum += spk;
    }
    // final output sigmoid(spksum/10)
    float e = __builtin_amdgcn_exp2f(spksum * -0.14426950408f);
    out[b0 + tid] = __builtin_amdgcn_rcpf(1.0f + e);   // FLOAT32 output
  }
}

extern "C" void kernel_launch(void* const* d_in, const int* in_sizes, int n_in,
                              void* d_out, int out_size, void* d_ws, size_t ws_size,
                              hipStream_t stream) {
  const float* x  = (const float*)d_in[0];
  const float* W1 = (const float*)d_in[1];
  const float* b1 = (const float*)d_in[2];
  const float* W2 = (const float*)d_in[3];
  const float* b2 = (const float*)d_in[4];
  float* out = (float*)d_out;
  (void)in_sizes; (void)n_in;

  const int grid = out_size / 32;   // out_size == B == 32768 -> 1024 blocks

  if (ws_size >= 512 * 256 * sizeof(unsigned short)) {
    unsigned short* w1bf = (unsigned short*)d_ws;   // 256 KB
    w1_to_bf16<<<128, 256, 0, stream>>>(W1, w1bf);
    snn_main<true><<<grid, 512, 0, stream>>>(x, w1bf, W1, b1, W2, b2, out);
  } else {
    snn_main<false><<<grid, 512, 0, stream>>>(x, nullptr, W1, b1, W2, b2, out);
  }
}

// Round 29
// 165.797 us; speedup vs baseline: 1.1630x; 1.0176x over previous
//
#include <hip/hip_runtime.h>
#include <hip/hip_bf16.h>

// FraudSNN fused kernel: GEMM (bf16 MFMA) + LIF recurrence, T=10, F=256, H=512.
// R29: fixes a pipelining bug present since R12: __syncthreads() emits
// s_waitcnt vmcnt(0) before s_barrier (guide §5), so pf(t+1) loads issued BEFORE
// the barrier were force-drained there -> prefetch latency fully exposed at every
// barrier. Now: issue pf loads AFTER the barrier (hidden under GEMM+LIF, 5-8K cyc),
// keep them as RAW float4 (pack deferred to next phase A, where the per-use waitcnt
// naturally lands). bfr0 (kk0 W1) stays pre-barrier (consumed right after - correct).
// Frame else = R28 (168.7us): 78KB LDS (2 blk/CU window), mem1 4 LDS + 4 reg planes,
// 1 barrier/t, deferred LIF2, parity-dbuf xt, setprio, exp2 sigmoid.

typedef short short8 __attribute__((ext_vector_type(8)));
typedef float f32x4 __attribute__((ext_vector_type(4)));

__device__ __forceinline__ unsigned short bfbits(float f) {
  union { __hip_bfloat16 h; unsigned short u; } c;
  c.h = __float2bfloat16(f);   // hardware RNE
  return c.u;
}

__device__ __forceinline__ unsigned int bfpack(float a, float b) {
  return (unsigned int)bfbits(a) | ((unsigned int)bfbits(b) << 16);
}

// sigmoid(10*(m-1)) = 1 / (1 + exp2(14.4269504*(1-m)))
__device__ __forceinline__ float spike10(float m) {
  float e = __builtin_amdgcn_exp2f(fmaf(m, -14.4269504f, 14.4269504f));
  return __builtin_amdgcn_rcpf(1.0f + e);
}

__device__ __forceinline__ void lif4(f32x4& mv, const f32x4 av, float w2c, float pr[4]) {
#pragma unroll
  for (int e = 0; e < 4; ++e) {
    float m   = fmaf(mv[e], 0.9f, av[e]);     // beta*mem + cur1
    float spk = spike10(m);
    mv[e] = m - spk;
    pr[e] = fmaf(spk, w2c, pr[e]);
  }
}

__global__ void w1_to_bf16(const float* __restrict__ w1, unsigned short* __restrict__ o) {
  int i = blockIdx.x * 256 + threadIdx.x;      // 32768 float4s
  float4 v = reinterpret_cast<const float4*>(w1)[i];
  reinterpret_cast<uint2*>(o)[i] = make_uint2(bfpack(v.x, v.y), bfpack(v.z, v.w));
}

__device__ __forceinline__ short8 cvt_frag(const float* p) {
  const float4 v0 = *reinterpret_cast<const float4*>(p);
  const float4 v1 = *reinterpret_cast<const float4*>(p + 4);
  union { unsigned int u[4]; short8 s; } cv;
  cv.u[0] = bfpack(v0.x, v0.y);
  cv.u[1] = bfpack(v0.z, v0.w);
  cv.u[2] = bfpack(v1.x, v1.y);
  cv.u[3] = bfpack(v1.z, v1.w);
  return cv.s;
}

// 512 threads = 8 waves. Block: 32 batch rows; wave w owns 32 rows x h in [w*64, w*64+64).
template <bool USE_WS>
__global__
__attribute__((amdgpu_flat_work_group_size(512, 512)))
void snn_main(const float* __restrict__ x,
              const unsigned short* __restrict__ w1bf,  // bf16 W1 (if USE_WS)
              const float* __restrict__ w1f,            // fp32 W1 (fallback)
              const float* __restrict__ b1,
              const float* __restrict__ w2,
              const float* __restrict__ b2,
              float* __restrict__ out)
{
  __shared__ __align__(16) float mem_lds[4][512][4];          // 32,768 B, 0-conflict slots
  __shared__ __align__(16) unsigned short xt[2][2][32][132];  // [par][half][row][col] 33,792 B
  __shared__ float cur2_lds[10][32][9];                       // [t][row][wave] 11,520 B
                                                              // total 78,080 B

  const int tid  = threadIdx.x;
  const int lane = tid & 63;
  const int wave = tid >> 6;          // 0..7
  const int l15  = lane & 15;
  const int lq   = lane >> 4;         // 0..3
  const long b0  = (long)blockIdx.x * 32;
  const int h0   = wave * 64;         // 4 col-tiles of 16

  float w2l[4], b1l[4];
#pragma unroll
  for (int ct = 0; ct < 4; ++ct) {
    int h = h0 + ct * 16 + l15;
    w2l[ct] = w2[h];
    b1l[ct] = b1[h];
  }

#pragma unroll
  for (int p = 0; p < 4; ++p) {
    f32x4 z = {0.f, 0.f, 0.f, 0.f};
    *reinterpret_cast<f32x4*>(&mem_lds[p][tid][0]) = z;
  }
  // planes 4..7 (rt1, all ct) in registers: 16 VGPR
  f32x4 m4 = {0.f, 0.f, 0.f, 0.f}, m5 = m4, m6 = m4, m7 = m4;

  // staging: thread -> row sr (0..31), float4 col sc (0..15); 4 float4 per t
  const int sr = tid >> 4;
  const int sc = tid & 15;
  const float* xrow = x + (b0 + sr) * 2560;

  const unsigned short* wb = w1bf + (h0 + l15) * 256 + lq * 8;
  const float*          wf = w1f  + (h0 + l15) * 256 + lq * 8;

  // prologue: RAW load of t=0 (pfr = 4 float4 = 16 VGPR; packed lazily at use)
  float4 pfr[4];
#pragma unroll
  for (int j = 0; j < 4; ++j)
    pfr[j] = *reinterpret_cast<const float4*>(xrow + (sc + j * 16) * 4);

#pragma unroll 1
  for (int t = 0; t < 10; ++t) {
    const int par = t & 1;
    // ---- A: pack pfr(t) -> xt[par]. The per-use waitcnt for pfr lands HERE,
    //      after a full phase of cover (loads were issued post-barrier last iter).
#pragma unroll
    for (int j = 0; j < 4; ++j)
      *reinterpret_cast<uint2*>(&xt[par][j >> 1][sr][(sc + (j & 1) * 16) * 4]) =
          make_uint2(bfpack(pfr[j].x, pfr[j].y), bfpack(pfr[j].z, pfr[j].w));
    // hoist kk=0 W1 fragments (consumed right after the barrier -> drain is correct)
    short8 bfr0[4];
#pragma unroll
    for (int c = 0; c < 4; ++c) {
      if constexpr (USE_WS) bfr0[c] = *reinterpret_cast<const short8*>(wb + c * 4096);
      else                  bfr0[c] = cvt_frag(wf + c * 4096);
    }
    __syncthreads();   // the ONLY per-t barrier: xt[par] visible

    // ---- issue pfr loads for t+1 AFTER the barrier: they stay in flight under the
    //      entire GEMM+LIF phase and are NOT drained until used in A(t+1). ----
    {
      const int tn = (t < 9) ? t + 1 : 9;   // tail: harmless re-read
#pragma unroll
      for (int j = 0; j < 4; ++j)
        pfr[j] = *reinterpret_cast<const float4*>(xrow + tn * 256 + (sc + j * 16) * 4);
    }

    // ---- single-pass GEMM: acc[2][4] = 32 regs, 8 MFMA per kk ----
    f32x4 acc[2][4];
#pragma unroll
    for (int rt = 0; rt < 2; ++rt)
#pragma unroll
      for (int c = 0; c < 4; ++c) {
        f32x4 cc = { b1l[c], b1l[c], b1l[c], b1l[c] };
        acc[rt][c] = cc;
      }

    __builtin_amdgcn_s_setprio(1);
#pragma unroll
    for (int kk = 0; kk < 8; ++kk) {
      short8 a[2], bfr[4];
#pragma unroll
      for (int rt = 0; rt < 2; ++rt)
        a[rt] = *reinterpret_cast<const short8*>(
            &xt[par][kk >> 2][rt * 16 + l15][(kk & 3) * 32 + lq * 8]);
      if (kk == 0) {
#pragma unroll
        for (int c = 0; c < 4; ++c) bfr[c] = bfr0[c];
      } else {
#pragma unroll
        for (int c = 0; c < 4; ++c) {
          if constexpr (USE_WS)
            bfr[c] = *reinterpret_cast<const short8*>(wb + c * 4096 + kk * 32);
          else
            bfr[c] = cvt_frag(wf + c * 4096 + kk * 32);
        }
      }
#pragma unroll
      for (int rt = 0; rt < 2; ++rt)
#pragma unroll
        for (int c = 0; c < 4; ++c)
          acc[rt][c] = __builtin_amdgcn_mfma_f32_16x16x32_bf16(a[rt], bfr[c], acc[rt][c], 0, 0, 0);
    }
    __builtin_amdgcn_s_setprio(0);

    // ---- LIF1 + partial W2 dot; planes 0..3 in LDS, 4..7 in regs ----
#pragma unroll
    for (int rt = 0; rt < 2; ++rt) {
      float pr[4] = {0.f, 0.f, 0.f, 0.f};
#pragma unroll
      for (int c = 0; c < 4; ++c) {
        const int p = rt * 4 + c;
        if (p < 4) {
          f32x4* slot = reinterpret_cast<f32x4*>(&mem_lds[p][tid][0]);
          f32x4 mv = *slot;
          lif4(mv, acc[rt][c], w2l[c], pr);
          *slot = mv;
        } else if (p == 4) {
          lif4(m4, acc[rt][c], w2l[c], pr);
        } else if (p == 5) {
          lif4(m5, acc[rt][c], w2l[c], pr);
        } else if (p == 6) {
          lif4(m6, acc[rt][c], w2l[c], pr);
        } else {
          lif4(m7, acc[rt][c], w2l[c], pr);
        }
      }
#pragma unroll
      for (int e = 0; e < 4; ++e) {
        float v = pr[e];
        v += __shfl_xor(v, 1); v += __shfl_xor(v, 2);
        v += __shfl_xor(v, 4); v += __shfl_xor(v, 8);
        if (l15 == 0) cur2_lds[t][rt * 16 + lq * 4 + e][wave] = v;
      }
    }
    // no second barrier: cur2_lds[t] is not read until after the final barrier
  }

  __syncthreads();   // final: all cur2 partials visible

  // ---- deferred LIF2: 10-step chain, once, on 32 threads ----
  if (tid < 32) {
    const float bias2 = b2[0];
    float mem2 = 0.f, spksum = 0.f;
#pragma unroll
    for (int t = 0; t < 10; ++t) {
      float c2 = bias2;
#pragma unroll
      for (int w = 0; w < 8; ++w) c2 += cur2_lds[t][tid][w];
      float m   = fmaf(mem2, 0.9f, c2);
      float spk = spike10(m);
      mem2   = m - spk;
      spksum += spk;
    }
    // final output sigmoid(spksum/10)
    float e = __builtin_amdgcn_exp2f(spksum * -0.14426950408f);
    out[b0 + tid] = __builtin_amdgcn_rcpf(1.0f + e);   // FLOAT32 output
  }
}

extern "C" void kernel_launch(void* const* d_in, const int* in_sizes, int n_in,
                              void* d_out, int out_size, void* d_ws, size_t ws_size,
                              hipStream_t stream) {
  const float* x  = (const float*)d_in[0];
  const float* W1 = (const float*)d_in[1];
  const float* b1 = (const float*)d_in[2];
  const float* W2 = (const float*)d_in[3];
  const float* b2 = (const float*)d_in[4];
  float* out = (float*)d_out;
  (void)in_sizes; (void)n_in;

  const int grid = out_size / 32;   // out_size == B == 32768 -> 1024 blocks

  if (ws_size >= 512 * 256 * sizeof(unsigned short)) {
    unsigned short* w1bf = (unsigned short*)d_ws;   // 256 KB
    w1_to_bf16<<<128, 256, 0, stream>>>(W1, w1bf);
    snn_main<true><<<grid, 512, 0, stream>>>(x, w1bf, W1, b1, W2, b2, out);
  } else {
    snn_main<false><<<grid, 512, 0, stream>>>(x, nullptr, W1, b1, W2, b2, out);
  }
}